// Round 4
// baseline (490.275 us; speedup 1.0000x reference)
//
#include <hip/hip_runtime.h>
#include <hip/hip_bf16.h>

typedef __attribute__((ext_vector_type(8))) short s16x8;
typedef __attribute__((ext_vector_type(4))) float f32x4;

#define WS_SEG 67108864ULL  // 64 MiB regions: [t/O][Q][K][Vt]

static __device__ __forceinline__ unsigned short f2bf(float f) {
    return __builtin_bit_cast(unsigned short, __float2bfloat16(f));   // RNE, lowers to v_cvt
}
static __device__ __forceinline__ unsigned int pack2(float a, float b) {
    return (unsigned int)f2bf(a) | ((unsigned int)f2bf(b) << 16);     // fuses to v_cvt_pk_bf16_f32
}
static __device__ __forceinline__ s16x8 u4cast(uint4 u) {
    return __builtin_bit_cast(s16x8, u);
}
// async global->LDS, 16B per lane; lds dest = wave-uniform base + lane*16
static __device__ __forceinline__ void gl_lds16(const void* g, void* l) {
    __builtin_amdgcn_global_load_lds(
        (const __attribute__((address_space(1))) unsigned int*)g,
        (__attribute__((address_space(3))) unsigned int*)l, 16, 0, 0);
}

// ---------------------------------------------------------------------------
// Weight convert f32 -> bf16, pre-swizzled: within each 128B k-chunk of a row,
// phys_cb = cb ^ ((row&7)<<4). Used for w_in (768x256) and w_out (256x256).
// ---------------------------------------------------------------------------
__global__ __launch_bounds__(256) void convw_swz(const float* __restrict__ wi,
                                                 unsigned short* __restrict__ wb) {
    int i = (blockIdx.x * 256 + threadIdx.x) * 4;   // element idx
    float4 v = *reinterpret_cast<const float4*>(wi + i);
    int bb = i * 2;                                  // byte addr in bf16 matrix
    int row = i >> 8;
    int dst = (bb & ~127) | ((bb & 127) ^ ((row & 7) << 4));
    uint2 o = { pack2(v.x, v.y), pack2(v.z, v.w) };
    *reinterpret_cast<uint2*>((char*)wb + dst) = o;
}

// ---------------------------------------------------------------------------
// Patch gather x[2,256,256,256] f32 -> t bf16 [131072][256], pre-swizzled.
// ---------------------------------------------------------------------------
__global__ __launch_bounds__(256) void gather_swz(const float* __restrict__ x,
                                                  unsigned short* __restrict__ t) {
    int q = (blockIdx.x * 256 + threadIdx.x) * 4;
    int e = q & 255, c = (q >> 8) & 255, n = q >> 16;
    int b = n >> 8, p = n & 255;
    int xi = ((b * 256 + c) * 256 + (p >> 4) * 16 + (e >> 4)) * 256 + (p & 15) * 16 + (e & 15);
    float4 v = *reinterpret_cast<const float4*>(x + xi);
    int bb = q * 2;
    int row = q >> 8;
    int dst = (bb & ~127) | ((bb & 127) ^ ((row & 7) << 4));
    uint2 o = { pack2(v.x, v.y), pack2(v.z, v.w) };
    *reinterpret_cast<uint2*>((char*)t + dst) = o;
}

// ---------------------------------------------------------------------------
// GEMM: C[M][N] = A @ W^T + bias. A,W bf16 [*][256] PRE-SWIZZLED.
// 128x128 tile, BK=64, 4 waves (2x2 -> 64x64 each), global_load_lds staging.
// MODE 0: N=768 (grid.x=6). Epilogue: LDS transpose -> coalesced stores to
//         Q/K [nh][c][64] and Vt [nh][64][c] (all LINEAR bf16).
// MODE 1: N=256 (grid.x=2). Epilogue: direct f32 stores to out [b][c][p][e].
// ---------------------------------------------------------------------------
template<int MODE>
__global__ __launch_bounds__(256) void gemm3(
    const unsigned short* __restrict__ A,
    const unsigned short* __restrict__ Wb,
    const float* __restrict__ bias,
    unsigned short* __restrict__ Qo, unsigned short* __restrict__ Ko,
    unsigned short* __restrict__ Vt, float* __restrict__ Out)
{
    __shared__ __align__(16) char smem[32768];
    char* AsB = smem;            // 16KB: [128 rows][128B], swizzled
    char* BsB = smem + 16384;

    const int t = threadIdx.x, w = t >> 6, lane = t & 63;
    const int lr = lane & 15, lk = lane >> 4;
    const int wm = w >> 1, wn = w & 1;
    const int bn = blockIdx.x, bm = blockIdx.y;

    f32x4 acc[4][4] = {};

    const char* Ag = (const char*)A + (size_t)bm * 65536;   // 128 rows * 512B
    const char* Bg = (const char*)Wb + (size_t)bn * 65536;

    for (int kk = 0; kk < 4; ++kk) {
        #pragma unroll
        for (int i = 0; i < 4; ++i) {
            int u = (i * 4 + w) * 64 + lane;          // 0..1023 (16B units)
            int row = u >> 3, cb = (u & 7) * 16;
            gl_lds16(Ag + row * 512 + kk * 128 + cb, AsB + (i * 4 + w) * 1024);
            gl_lds16(Bg + row * 512 + kk * 128 + cb, BsB + (i * 4 + w) * 1024);
        }
        __syncthreads();
        #pragma unroll
        for (int kc = 0; kc < 2; ++kc) {
            s16x8 af[4], bf[4];
            #pragma unroll
            for (int fm = 0; fm < 4; ++fm) {
                int r = wm * 64 + fm * 16 + lr;
                af[fm] = *reinterpret_cast<const s16x8*>(
                    AsB + r * 128 + ((kc * 64 + lk * 16) ^ ((r & 7) << 4)));
            }
            #pragma unroll
            for (int fn = 0; fn < 4; ++fn) {
                int cc = wn * 64 + fn * 16 + lr;
                bf[fn] = *reinterpret_cast<const s16x8*>(
                    BsB + cc * 128 + ((kc * 64 + lk * 16) ^ ((cc & 7) << 4)));
            }
            #pragma unroll
            for (int fm = 0; fm < 4; ++fm)
                #pragma unroll
                for (int fn = 0; fn < 4; ++fn)
                    acc[fm][fn] = __builtin_amdgcn_mfma_f32_16x16x32_bf16(af[fm], bf[fn], acc[fm][fn], 0, 0, 0);
        }
        __syncthreads();
    }

    if (MODE == 1) {
        #pragma unroll
        for (int fn = 0; fn < 4; ++fn) {
            int colg = bn * 128 + wn * 64 + fn * 16 + lr;
            float bv = bias[colg];
            #pragma unroll
            for (int fm = 0; fm < 4; ++fm)
                #pragma unroll
                for (int j = 0; j < 4; ++j) {
                    int rg = bm * 128 + wm * 64 + fm * 16 + lk * 4 + j;
                    int n = rg >> 8, c = rg & 255;
                    int b = n >> 8, p = n & 255;
                    Out[(((b * 256 + c) * 256 + p) << 8) + colg] = acc[fm][fn][j] + bv;
                }
        }
        return;
    }

    // ---- MODE 0 epilogue: transpose through LDS (smem reused; k-loop ended
    // with a barrier so As/Bs are dead).
    unsigned short* T = (unsigned short*)smem;
    const int X = bn >> 1;            // 0=Q, 1=K, 2=V
    const int h0 = (bn & 1) * 2;
    const int n = bm >> 1;

    #pragma unroll
    for (int fn = 0; fn < 4; ++fn) {
        int col_local = wn * 64 + fn * 16 + lr;       // 0..127
        float bv = bias[bn * 128 + col_local];
        #pragma unroll
        for (int fm = 0; fm < 4; ++fm)
            #pragma unroll
            for (int j = 0; j < 4; ++j) {
                int c_local = wm * 64 + fm * 16 + lk * 4 + j;   // 0..127
                unsigned short hv = f2bf(acc[fm][fn][j] + bv);
                if (X < 2) {
                    *reinterpret_cast<unsigned short*>(
                        (char*)T + c_local * 256 + col_local * 2) = hv;
                } else {
                    int hl = col_local >> 6, d = col_local & 63;
                    *reinterpret_cast<unsigned short*>(
                        (char*)T + hl * 16384 + d * 256 + ((c_local * 2) ^ ((d & 7) << 4))) = hv;
                }
            }
    }
    __syncthreads();

    if (X < 2) {
        unsigned short* base = (X == 0) ? Qo : Ko;
        #pragma unroll
        for (int i = 0; i < 8; ++i) {
            int u = i * 256 + t;                 // 16B units, 2048 total
            int c_local = u >> 4;
            int cbyte = (u & 15) * 16;           // 0..255 across 2 heads
            int h = h0 + (cbyte >> 7);
            int db = cbyte & 127;
            uint4 vv = *reinterpret_cast<const uint4*>((char*)T + u * 16);
            int c = (bm & 1) * 128 + c_local;
            *reinterpret_cast<uint4*>(
                (char*)base + (size_t)((n * 4 + h) * 256 + c) * 128 + db) = vv;
        }
    } else {
        #pragma unroll
        for (int i = 0; i < 8; ++i) {
            int u = i * 256 + t;
            int rowr = u >> 4;                   // 0..127 (2 heads x 64 d)
            int hl = rowr >> 6, d = rowr & 63;
            int cb2 = (u & 15) * 16;
            int c2 = cb2 ^ ((d & 7) << 4);       // un-swizzle -> logical c byte
            uint4 vv = *reinterpret_cast<const uint4*>((char*)T + u * 16);
            *reinterpret_cast<uint4*>(
                (char*)Vt + (size_t)((n * 4 + h0 + hl) * 64 + d) * 512 + (bm & 1) * 256 + c2) = vv;
        }
    }
}

// ---------------------------------------------------------------------------
// Attention v5. One block of 512 threads (8 waves) per (n,h); K AND V in LDS
// (XOR-swizzled). Each wave owns 2 q-tiles of 16 rows. In-register softmax;
// exp fused with bf16 pack (pack-early: s[] dies into pf[] -> VGPR<=128 ->
// 16 waves/CU). O stored pre-swizzled for gemm3<1>.
// ---------------------------------------------------------------------------
__global__ __launch_bounds__(512, 4) void attn5(
    const unsigned short* __restrict__ Q,
    const unsigned short* __restrict__ K,
    const unsigned short* __restrict__ V,
    unsigned short* __restrict__ O)
{
    __shared__ __align__(16) char KsB[32768];     // [256 key][128B] swizzled
    __shared__ __align__(16) char VsB[32768];     // [64 d][512B] swizzled
    __shared__ __align__(16) char OtrB[8][2048];  // per-wave transpose

    const int nh = blockIdx.x;
    const int n = nh >> 2, h = nh & 3;
    const int t = threadIdx.x, w = t >> 6, lane = t & 63;
    const int lr = lane & 15, lk = lane >> 4;

    const unsigned short* Qg = Q + (size_t)nh * 16384;
    const char* Kg = (const char*)K + (size_t)nh * 32768;
    const char* Vg = (const char*)V + (size_t)nh * 32768;

    #pragma unroll
    for (int i = 0; i < 4; ++i) {                 // stage K (2048 16B units)
        int u = i * 512 + t;
        int row = u >> 3, cb = (u & 7) * 16;
        uint4 val = *reinterpret_cast<const uint4*>(Kg + u * 16);
        *reinterpret_cast<uint4*>(KsB + row * 128 + (cb ^ ((row & 7) << 4))) = val;
    }
    #pragma unroll
    for (int i = 0; i < 4; ++i) {                 // stage V
        int u = i * 512 + t;
        int row = u >> 5, cb = (u & 31) * 16;
        uint4 val = *reinterpret_cast<const uint4*>(Vg + u * 16);
        *reinterpret_cast<uint4*>(VsB + row * 512 + (cb ^ ((row & 7) << 4))) = val;
    }
    __syncthreads();

    const float sc = 0.125f * 1.44269504f;   // HD^-0.5 * log2(e)

    #pragma unroll
    for (int it = 0; it < 2; ++it) {
        const int qt = w * 2 + it;

        s16x8 bq0 = *reinterpret_cast<const s16x8*>(Qg + (qt * 16 + lr) * 64 + lk * 8);
        s16x8 bq1 = *reinterpret_cast<const s16x8*>(Qg + (qt * 16 + lr) * 64 + 32 + lk * 8);

        // S^T: lane holds S[key = 16*kt + 4*lk + j][q = qt*16+lr]
        f32x4 s[16];
        #pragma unroll
        for (int kt = 0; kt < 16; ++kt) {
            const int rb = (kt * 16 + lr) * 128;
            const int swz = (lr & 7) << 4;
            s16x8 a0 = *reinterpret_cast<const s16x8*>(KsB + rb + ((lk * 16) ^ swz));
            s16x8 a1 = *reinterpret_cast<const s16x8*>(KsB + rb + ((64 + lk * 16) ^ swz));
            f32x4 z = { 0.f, 0.f, 0.f, 0.f };
            z = __builtin_amdgcn_mfma_f32_16x16x32_bf16(a0, bq0, z, 0, 0, 0);
            z = __builtin_amdgcn_mfma_f32_16x16x32_bf16(a1, bq1, z, 0, 0, 0);
            s[kt] = z;
        }

        // max over 256 keys (64 local + cross-lk shfl)
        float m = fmaxf(fmaxf(s[0][0], s[0][1]), fmaxf(s[0][2], s[0][3]));
        #pragma unroll
        for (int kt = 1; kt < 16; ++kt)
            m = fmaxf(m, fmaxf(fmaxf(s[kt][0], s[kt][1]), fmaxf(s[kt][2], s[kt][3])));
        m = fmaxf(m, __shfl_xor(m, 16));
        m = fmaxf(m, __shfl_xor(m, 32));

        // exp fused with pack: s[] dies into pf[] (permuted-key bijection)
        const float nb = -m * sc;
        float l = 0.f;
        s16x8 pf[8];
        #pragma unroll
        for (int kb = 0; kb < 8; ++kb) {
            float p0 = exp2f(__builtin_fmaf(s[2 * kb][0], sc, nb));
            float p1 = exp2f(__builtin_fmaf(s[2 * kb][1], sc, nb));
            float p2 = exp2f(__builtin_fmaf(s[2 * kb][2], sc, nb));
            float p3 = exp2f(__builtin_fmaf(s[2 * kb][3], sc, nb));
            float p4 = exp2f(__builtin_fmaf(s[2 * kb + 1][0], sc, nb));
            float p5 = exp2f(__builtin_fmaf(s[2 * kb + 1][1], sc, nb));
            float p6 = exp2f(__builtin_fmaf(s[2 * kb + 1][2], sc, nb));
            float p7 = exp2f(__builtin_fmaf(s[2 * kb + 1][3], sc, nb));
            l += ((p0 + p1) + (p2 + p3)) + ((p4 + p5) + (p6 + p7));
            uint4 pk = { pack2(p0, p1), pack2(p2, p3), pack2(p4, p5), pack2(p6, p7) };
            pf[kb] = u4cast(pk);
        }
        l += __shfl_xor(l, 16);
        l += __shfl_xor(l, 32);

        // O^T = V^T @ P^T, V from LDS (swizzled), permuted-key bijection
        f32x4 oacc[4] = {};
        #pragma unroll
        for (int kb = 0; kb < 8; ++kb) {
            #pragma unroll
            for (int dt = 0; dt < 4; ++dt) {
                const int row = dt * 16 + lr;
                const char* vb = VsB + row * 512;
                const int swz = (lr & 7) << 4;
                uint2 v0 = *reinterpret_cast<const uint2*>(vb + ((kb * 64 + lk * 8) ^ swz));
                uint2 v1 = *reinterpret_cast<const uint2*>(vb + ((kb * 64 + lk * 8 + 32) ^ swz));
                uint4 uu = { v0.x, v0.y, v1.x, v1.y };
                oacc[dt] = __builtin_amdgcn_mfma_f32_16x16x32_bf16(u4cast(uu), pf[kb], oacc[dt], 0, 0, 0);
            }
        }

        // normalize; transpose via per-wave LDS; store PRE-SWIZZLED for gemm2
        const float rl = 1.0f / l;
        char* ob = OtrB[w];
        #pragma unroll
        for (int dt = 0; dt < 4; ++dt) {
            unsigned int w0 = pack2(oacc[dt][0] * rl, oacc[dt][1] * rl);
            unsigned int w1 = pack2(oacc[dt][2] * rl, oacc[dt][3] * rl);
            int cb0 = dt * 32 + lk * 8;
            int swz = (lr & 7) << 4;
            *reinterpret_cast<unsigned int*>(ob + lr * 128 + (cb0 ^ swz)) = w0;
            *reinterpret_cast<unsigned int*>(ob + lr * 128 + ((cb0 + 4) ^ swz)) = w1;
        }
        #pragma unroll
        for (int pp = 0; pp < 2; ++pp) {
            int qrow = lane >> 2;
            int cbX = (lane & 3) * 32 + pp * 16;   // PHYS offset (swizzles cancel)
            uint4 vv = *reinterpret_cast<const uint4*>(ob + qrow * 128 + cbX);
            *reinterpret_cast<uint4*>(
                (char*)O + (size_t)(n * 256 + qt * 16 + qrow) * 512 + h * 128 + cbX) = vv;
        }
    }
}

// ---------------------------------------------------------------------------
extern "C" void kernel_launch(void* const* d_in, const int* in_sizes, int n_in,
                              void* d_out, int out_size, void* d_ws, size_t ws_size,
                              hipStream_t stream) {
    const float* x     = (const float*)d_in[0];
    const float* w_in  = (const float*)d_in[1];
    const float* b_in  = (const float*)d_in[2];
    const float* w_out = (const float*)d_in[3];
    const float* b_out = (const float*)d_in[4];

    char* ws = (char*)d_ws;
    unsigned short* tO = (unsigned short*)(ws);               // t, later O
    unsigned short* Qw = (unsigned short*)(ws + WS_SEG);
    unsigned short* Kw = (unsigned short*)(ws + 2 * WS_SEG);
    unsigned short* Vw = (unsigned short*)(ws + 3 * WS_SEG);

    // bf16 w_in in d_out tail (read by gemm1, overwritten later by gemm2)
    unsigned short* WbIn = (unsigned short*)((float*)d_out + out_size - 98304);

    convw_swz<<<192, 256, 0, stream>>>(w_in, WbIn);
    gather_swz<<<32768, 256, 0, stream>>>(x, tO);

    gemm3<0><<<dim3(6, 1024), 256, 0, stream>>>(tO, WbIn, b_in, Qw, Kw, Vw, nullptr);

    attn5<<<2048, 512, 0, stream>>>(Qw, Kw, Vw, tO);          // O overwrites t

    unsigned short* WbOut = Kw;                               // K dead after attn
    convw_swz<<<64, 256, 0, stream>>>(w_out, WbOut);

    gemm3<1><<<dim3(2, 1024), 256, 0, stream>>>(tO, WbOut, b_out,
                                                nullptr, nullptr, nullptr, (float*)d_out);
}

// Round 5
// 304.551 us; speedup vs baseline: 1.6098x; 1.6098x over previous
//
#include <hip/hip_runtime.h>
#include <hip/hip_bf16.h>

typedef __attribute__((ext_vector_type(8))) short s16x8;
typedef __attribute__((ext_vector_type(4))) float f32x4;

#define WS_SEG 67108864ULL  // 64 MiB regions: [t/O][Q][K][Vt]

#if defined(__has_attribute)
#if __has_attribute(amdgpu_num_vgpr)
#define VGPR_CAP_128 __attribute__((amdgpu_num_vgpr(128)))
#else
#define VGPR_CAP_128
#endif
#else
#define VGPR_CAP_128
#endif

static __device__ __forceinline__ unsigned short f2bf(float f) {
    return __builtin_bit_cast(unsigned short, __float2bfloat16(f));   // RNE v_cvt
}
static __device__ __forceinline__ unsigned int pack2(float a, float b) {
    return (unsigned int)f2bf(a) | ((unsigned int)f2bf(b) << 16);     // v_cvt_pk path
}
static __device__ __forceinline__ s16x8 u4cast(uint4 u) {
    return __builtin_bit_cast(s16x8, u);
}
// async global->LDS, 16B per lane; lds dest = wave-uniform base + lane*16
static __device__ __forceinline__ void gl_lds16(const void* g, void* l) {
    __builtin_amdgcn_global_load_lds(
        (const __attribute__((address_space(1))) unsigned int*)g,
        (__attribute__((address_space(3))) unsigned int*)l, 16, 0, 0);
}

// ---------------------------------------------------------------------------
// Weight convert f32 -> bf16, pre-swizzled: within each 128B k-chunk of a row,
// phys_cb = cb ^ ((row&7)<<4).
// ---------------------------------------------------------------------------
__global__ __launch_bounds__(256) void convw_swz(const float* __restrict__ wi,
                                                 unsigned short* __restrict__ wb) {
    int i = (blockIdx.x * 256 + threadIdx.x) * 4;   // element idx
    float4 v = *reinterpret_cast<const float4*>(wi + i);
    int bb = i * 2;                                  // byte addr in bf16 matrix
    int row = i >> 8;
    int dst = (bb & ~127) | ((bb & 127) ^ ((row & 7) << 4));
    uint2 o = { pack2(v.x, v.y), pack2(v.z, v.w) };
    *reinterpret_cast<uint2*>((char*)wb + dst) = o;
}

// ---------------------------------------------------------------------------
// Patch gather x[2,256,256,256] f32 -> t bf16 [131072][256], pre-swizzled.
// ---------------------------------------------------------------------------
__global__ __launch_bounds__(256) void gather_swz(const float* __restrict__ x,
                                                  unsigned short* __restrict__ t) {
    int q = (blockIdx.x * 256 + threadIdx.x) * 4;
    int e = q & 255, c = (q >> 8) & 255, n = q >> 16;
    int b = n >> 8, p = n & 255;
    int xi = ((b * 256 + c) * 256 + (p >> 4) * 16 + (e >> 4)) * 256 + (p & 15) * 16 + (e & 15);
    float4 v = *reinterpret_cast<const float4*>(x + xi);
    int bb = q * 2;
    int row = q >> 8;
    int dst = (bb & ~127) | ((bb & 127) ^ ((row & 7) << 4));
    uint2 o = { pack2(v.x, v.y), pack2(v.z, v.w) };
    *reinterpret_cast<uint2*>((char*)t + dst) = o;
}

// ---------------------------------------------------------------------------
// GEMM: C[M][N] = A @ W^T + bias. A,W bf16 [*][256] PRE-SWIZZLED.
// 128x128 tile, BK=64, 4 waves (2x2), global_load_lds staging.
// 1-D grid with XCD-chunked remap: the NB blocks sharing an A-tile run
// back-to-back on ONE XCD -> A re-reads hit that XCD's L2.
// MODE 0: N=768 (NB=6), epilogue scatters Q/K [nh][c][64], Vt [nh][64][c].
// MODE 1: N=256 (NB=2), epilogue stores f32 out [b][c][p][e].
// ---------------------------------------------------------------------------
template<int MODE>
__global__ __launch_bounds__(256) void gemm3(
    const unsigned short* __restrict__ A,
    const unsigned short* __restrict__ Wb,
    const float* __restrict__ bias,
    unsigned short* __restrict__ Qo, unsigned short* __restrict__ Ko,
    unsigned short* __restrict__ Vt, float* __restrict__ Out)
{
    __shared__ __align__(16) char smem[32768];
    char* AsB = smem;            // 16KB: [128 rows][128B], swizzled
    char* BsB = smem + 16384;

    const int t = threadIdx.x, w = t >> 6, lane = t & 63;
    const int lr = lane & 15, lk = lane >> 4;
    const int wm = w >> 1, wn = w & 1;

    constexpr int NB = (MODE == 0) ? 6 : 2;
    const int flat = blockIdx.x;
    const int xcd = flat & 7, idx = flat >> 3;
    const int bm = xcd * 128 + idx / NB;     // 128 consecutive A-tiles per XCD
    const int bn = idx % NB;

    f32x4 acc[4][4] = {};

    const char* Ag = (const char*)A + (size_t)bm * 65536;   // 128 rows * 512B
    const char* Bg = (const char*)Wb + (size_t)bn * 65536;

    for (int kk = 0; kk < 4; ++kk) {
        #pragma unroll
        for (int i = 0; i < 4; ++i) {
            int u = (i * 4 + w) * 64 + lane;          // 0..1023 (16B units)
            int row = u >> 3, cb = (u & 7) * 16;
            gl_lds16(Ag + row * 512 + kk * 128 + cb, AsB + (i * 4 + w) * 1024);
            gl_lds16(Bg + row * 512 + kk * 128 + cb, BsB + (i * 4 + w) * 1024);
        }
        __syncthreads();
        #pragma unroll
        for (int kc = 0; kc < 2; ++kc) {
            s16x8 af[4], bf[4];
            #pragma unroll
            for (int fm = 0; fm < 4; ++fm) {
                int r = wm * 64 + fm * 16 + lr;
                af[fm] = *reinterpret_cast<const s16x8*>(
                    AsB + r * 128 + ((kc * 64 + lk * 16) ^ ((r & 7) << 4)));
            }
            #pragma unroll
            for (int fn = 0; fn < 4; ++fn) {
                int cc = wn * 64 + fn * 16 + lr;
                bf[fn] = *reinterpret_cast<const s16x8*>(
                    BsB + cc * 128 + ((kc * 64 + lk * 16) ^ ((cc & 7) << 4)));
            }
            __builtin_amdgcn_s_setprio(1);
            #pragma unroll
            for (int fm = 0; fm < 4; ++fm)
                #pragma unroll
                for (int fn = 0; fn < 4; ++fn)
                    acc[fm][fn] = __builtin_amdgcn_mfma_f32_16x16x32_bf16(af[fm], bf[fn], acc[fm][fn], 0, 0, 0);
            __builtin_amdgcn_s_setprio(0);
        }
        __syncthreads();
    }

    if (MODE == 1) {
        #pragma unroll
        for (int fn = 0; fn < 4; ++fn) {
            int colg = bn * 128 + wn * 64 + fn * 16 + lr;
            float bv = bias[colg];
            #pragma unroll
            for (int fm = 0; fm < 4; ++fm)
                #pragma unroll
                for (int j = 0; j < 4; ++j) {
                    int rg = bm * 128 + wm * 64 + fm * 16 + lk * 4 + j;
                    int n = rg >> 8, c = rg & 255;
                    int b = n >> 8, p = n & 255;
                    Out[(((b * 256 + c) * 256 + p) << 8) + colg] = acc[fm][fn][j] + bv;
                }
        }
        return;
    }

    // ---- MODE 0 epilogue: transpose through LDS (As/Bs dead after barrier).
    unsigned short* T = (unsigned short*)smem;
    const int X = bn >> 1;            // 0=Q, 1=K, 2=V
    const int h0 = (bn & 1) * 2;
    const int n = bm >> 1;

    #pragma unroll
    for (int fn = 0; fn < 4; ++fn) {
        int col_local = wn * 64 + fn * 16 + lr;       // 0..127
        float bv = bias[bn * 128 + col_local];
        #pragma unroll
        for (int fm = 0; fm < 4; ++fm)
            #pragma unroll
            for (int j = 0; j < 4; ++j) {
                int c_local = wm * 64 + fm * 16 + lk * 4 + j;   // 0..127
                unsigned short hv = f2bf(acc[fm][fn][j] + bv);
                if (X < 2) {
                    *reinterpret_cast<unsigned short*>(
                        (char*)T + c_local * 256 + col_local * 2) = hv;
                } else {
                    int hl = col_local >> 6, d = col_local & 63;
                    *reinterpret_cast<unsigned short*>(
                        (char*)T + hl * 16384 + d * 256 + ((c_local * 2) ^ ((d & 7) << 4))) = hv;
                }
            }
    }
    __syncthreads();

    if (X < 2) {
        unsigned short* base = (X == 0) ? Qo : Ko;
        #pragma unroll
        for (int i = 0; i < 8; ++i) {
            int u = i * 256 + t;                 // 16B units, 2048 total
            int c_local = u >> 4;
            int cbyte = (u & 15) * 16;           // 0..255 across 2 heads
            int h = h0 + (cbyte >> 7);
            int db = cbyte & 127;
            uint4 vv = *reinterpret_cast<const uint4*>((char*)T + u * 16);
            int c = (bm & 1) * 128 + c_local;
            *reinterpret_cast<uint4*>(
                (char*)base + (size_t)((n * 4 + h) * 256 + c) * 128 + db) = vv;
        }
    } else {
        #pragma unroll
        for (int i = 0; i < 8; ++i) {
            int u = i * 256 + t;
            int rowr = u >> 4;                   // 0..127 (2 heads x 64 d)
            int hl = rowr >> 6, d = rowr & 63;
            int cb2 = (u & 15) * 16;
            int c2 = cb2 ^ ((d & 7) << 4);       // un-swizzle -> logical c byte
            uint4 vv = *reinterpret_cast<const uint4*>((char*)T + u * 16);
            *reinterpret_cast<uint4*>(
                (char*)Vt + (size_t)((n * 4 + h0 + hl) * 64 + d) * 512 + (bm & 1) * 256 + c2) = vv;
        }
    }
}

// ---------------------------------------------------------------------------
// Attention v6. One 512-thread block (8 waves) per (n,h); K+V in LDS
// (XOR-swizzled, 64KB) + 16KB Otr = 80KB -> 2 blocks/CU iff VGPR<=128
// (requested via amdgpu_num_vgpr; pack-early keeps liveness ~100).
// Tree-reduced softmax; setprio around MFMA clusters.
// ---------------------------------------------------------------------------
__global__ __launch_bounds__(512) VGPR_CAP_128 void attn6(
    const unsigned short* __restrict__ Q,
    const unsigned short* __restrict__ K,
    const unsigned short* __restrict__ V,
    unsigned short* __restrict__ O)
{
    __shared__ __align__(16) char KsB[32768];     // [256 key][128B] swizzled
    __shared__ __align__(16) char VsB[32768];     // [64 d][512B] swizzled
    __shared__ __align__(16) char OtrB[8][2048];  // per-wave transpose

    const int nh = blockIdx.x;
    const int n = nh >> 2, h = nh & 3;
    const int t = threadIdx.x, w = t >> 6, lane = t & 63;
    const int lr = lane & 15, lk = lane >> 4;

    const unsigned short* Qg = Q + (size_t)nh * 16384;
    const char* Kg = (const char*)K + (size_t)nh * 32768;
    const char* Vg = (const char*)V + (size_t)nh * 32768;

    #pragma unroll
    for (int i = 0; i < 4; ++i) {                 // stage K (2048 16B units)
        int u = i * 512 + t;
        int row = u >> 3, cb = (u & 7) * 16;
        uint4 val = *reinterpret_cast<const uint4*>(Kg + u * 16);
        *reinterpret_cast<uint4*>(KsB + row * 128 + (cb ^ ((row & 7) << 4))) = val;
    }
    #pragma unroll
    for (int i = 0; i < 4; ++i) {                 // stage V
        int u = i * 512 + t;
        int row = u >> 5, cb = (u & 31) * 16;
        uint4 val = *reinterpret_cast<const uint4*>(Vg + u * 16);
        *reinterpret_cast<uint4*>(VsB + row * 512 + (cb ^ ((row & 7) << 4))) = val;
    }
    __syncthreads();

    const float sc = 0.125f * 1.44269504f;   // HD^-0.5 * log2(e)
    const int swz = (lr & 7) << 4;

    #pragma unroll
    for (int it = 0; it < 2; ++it) {
        const int qt = w * 2 + it;

        s16x8 bq0 = *reinterpret_cast<const s16x8*>(Qg + (qt * 16 + lr) * 64 + lk * 8);
        s16x8 bq1 = *reinterpret_cast<const s16x8*>(Qg + (qt * 16 + lr) * 64 + 32 + lk * 8);

        // S^T: lane holds S[key = 16*kt + 4*lk + j][q = qt*16+lr]
        f32x4 s[16];
        #pragma unroll
        for (int kt = 0; kt < 16; ++kt) {
            const int rb = (kt * 16 + lr) * 128;
            s16x8 a0 = *reinterpret_cast<const s16x8*>(KsB + rb + ((lk * 16) ^ swz));
            s16x8 a1 = *reinterpret_cast<const s16x8*>(KsB + rb + ((64 + lk * 16) ^ swz));
            f32x4 z = { 0.f, 0.f, 0.f, 0.f };
            __builtin_amdgcn_s_setprio(1);
            z = __builtin_amdgcn_mfma_f32_16x16x32_bf16(a0, bq0, z, 0, 0, 0);
            z = __builtin_amdgcn_mfma_f32_16x16x32_bf16(a1, bq1, z, 0, 0, 0);
            __builtin_amdgcn_s_setprio(0);
            s[kt] = z;
        }

        // tree max over 256 keys (depth ~6 local + 2 shfl)
        float m8[8];
        #pragma unroll
        for (int i = 0; i < 8; ++i) {
            float a = fmaxf(fmaxf(s[i][0], s[i][1]), fmaxf(s[i][2], s[i][3]));
            float b = fmaxf(fmaxf(s[i + 8][0], s[i + 8][1]), fmaxf(s[i + 8][2], s[i + 8][3]));
            m8[i] = fmaxf(a, b);
        }
        float m = fmaxf(fmaxf(fmaxf(m8[0], m8[1]), fmaxf(m8[2], m8[3])),
                        fmaxf(fmaxf(m8[4], m8[5]), fmaxf(m8[6], m8[7])));
        m = fmaxf(m, __shfl_xor(m, 16));
        m = fmaxf(m, __shfl_xor(m, 32));

        // exp fused with pack: s[] dies into pf[] (permuted-key bijection)
        const float nb = -m * sc;
        float lp[8];
        s16x8 pf[8];
        #pragma unroll
        for (int kb = 0; kb < 8; ++kb) {
            float p0 = exp2f(__builtin_fmaf(s[2 * kb][0], sc, nb));
            float p1 = exp2f(__builtin_fmaf(s[2 * kb][1], sc, nb));
            float p2 = exp2f(__builtin_fmaf(s[2 * kb][2], sc, nb));
            float p3 = exp2f(__builtin_fmaf(s[2 * kb][3], sc, nb));
            float p4 = exp2f(__builtin_fmaf(s[2 * kb + 1][0], sc, nb));
            float p5 = exp2f(__builtin_fmaf(s[2 * kb + 1][1], sc, nb));
            float p6 = exp2f(__builtin_fmaf(s[2 * kb + 1][2], sc, nb));
            float p7 = exp2f(__builtin_fmaf(s[2 * kb + 1][3], sc, nb));
            lp[kb] = ((p0 + p1) + (p2 + p3)) + ((p4 + p5) + (p6 + p7));
            uint4 pk = { pack2(p0, p1), pack2(p2, p3), pack2(p4, p5), pack2(p6, p7) };
            pf[kb] = u4cast(pk);
        }
        float l = ((lp[0] + lp[1]) + (lp[2] + lp[3])) + ((lp[4] + lp[5]) + (lp[6] + lp[7]));
        l += __shfl_xor(l, 16);
        l += __shfl_xor(l, 32);

        // O^T = V^T @ P^T, V from LDS (swizzled), permuted-key bijection
        f32x4 oacc[4] = {};
        #pragma unroll
        for (int kb = 0; kb < 8; ++kb) {
            #pragma unroll
            for (int dt = 0; dt < 4; ++dt) {
                const char* vb = VsB + (dt * 16 + lr) * 512;
                uint2 v0 = *reinterpret_cast<const uint2*>(vb + ((kb * 64 + lk * 8) ^ swz));
                uint2 v1 = *reinterpret_cast<const uint2*>(vb + ((kb * 64 + lk * 8 + 32) ^ swz));
                uint4 uu = { v0.x, v0.y, v1.x, v1.y };
                __builtin_amdgcn_s_setprio(1);
                oacc[dt] = __builtin_amdgcn_mfma_f32_16x16x32_bf16(u4cast(uu), pf[kb], oacc[dt], 0, 0, 0);
                __builtin_amdgcn_s_setprio(0);
            }
        }

        // normalize; transpose via per-wave LDS; store PRE-SWIZZLED for gemm2
        const float rl = 1.0f / l;
        char* ob = OtrB[w];
        #pragma unroll
        for (int dt = 0; dt < 4; ++dt) {
            unsigned int w0 = pack2(oacc[dt][0] * rl, oacc[dt][1] * rl);
            unsigned int w1 = pack2(oacc[dt][2] * rl, oacc[dt][3] * rl);
            int cb0 = dt * 32 + lk * 8;
            *reinterpret_cast<unsigned int*>(ob + lr * 128 + (cb0 ^ swz)) = w0;
            *reinterpret_cast<unsigned int*>(ob + lr * 128 + ((cb0 + 4) ^ swz)) = w1;
        }
        #pragma unroll
        for (int pp = 0; pp < 2; ++pp) {
            int qrow = lane >> 2;
            int cbX = (lane & 3) * 32 + pp * 16;   // PHYS offset (swizzles cancel)
            uint4 vv = *reinterpret_cast<const uint4*>(ob + qrow * 128 + cbX);
            *reinterpret_cast<uint4*>(
                (char*)O + (size_t)(n * 256 + qt * 16 + qrow) * 512 + h * 128 + cbX) = vv;
        }
    }
}

// ---------------------------------------------------------------------------
extern "C" void kernel_launch(void* const* d_in, const int* in_sizes, int n_in,
                              void* d_out, int out_size, void* d_ws, size_t ws_size,
                              hipStream_t stream) {
    const float* x     = (const float*)d_in[0];
    const float* w_in  = (const float*)d_in[1];
    const float* b_in  = (const float*)d_in[2];
    const float* w_out = (const float*)d_in[3];
    const float* b_out = (const float*)d_in[4];

    char* ws = (char*)d_ws;
    unsigned short* tO = (unsigned short*)(ws);               // t, later O
    unsigned short* Qw = (unsigned short*)(ws + WS_SEG);
    unsigned short* Kw = (unsigned short*)(ws + 2 * WS_SEG);
    unsigned short* Vw = (unsigned short*)(ws + 3 * WS_SEG);

    // bf16 w_in in d_out tail (read by gemm1, overwritten later by gemm2)
    unsigned short* WbIn = (unsigned short*)((float*)d_out + out_size - 98304);

    convw_swz<<<192, 256, 0, stream>>>(w_in, WbIn);
    gather_swz<<<32768, 256, 0, stream>>>(x, tO);

    gemm3<0><<<6144, 256, 0, stream>>>(tO, WbIn, b_in, Qw, Kw, Vw, nullptr);

    attn6<<<2048, 512, 0, stream>>>(Qw, Kw, Vw, tO);          // O overwrites t

    unsigned short* WbOut = Kw;                               // K dead after attn
    convw_swz<<<64, 256, 0, stream>>>(w_out, WbOut);

    gemm3<1><<<2048, 256, 0, stream>>>(tO, WbOut, b_out,
                                       nullptr, nullptr, nullptr, (float*)d_out);
}